// Round 6
// baseline (1021.314 us; speedup 1.0000x reference)
//
#include <hip/hip_runtime.h>
#include <math.h>

#define EPS 1e-9f

constexpr int B_ = 8, N_ = 2048, M_ = 2048;
constexpr int THREADS = 1024;              // 16 waves/block
constexpr int WAVES = 16;
constexpr int RPW = 2;                     // rows per wave
constexpr int RPB = WAVES * RPW;           // 32 rows per block
constexpr int BPB = N_ / RPB;              // 64 blocks per batch
constexpr int GRID = B_ * BPB;             // 512 blocks = 2/CU -> 32 waves/CU (HW max)

__global__ __launch_bounds__(256) void init_kernel(float* rL, float* fb,
                                                   float* ss0, float* out) {
    int i = blockIdx.x * blockDim.x + threadIdx.x;
    if (i < B_ * N_) { rL[i] = 1.f; fb[i] = 0.f; ss0[i] = 0.f; }
    if (i < B_) out[i] = 0.f;
}

// Multi-kernel skeleton (best family). Round-6 changes:
//  - Round-3's 8-waves/SIMD geometry REINSTATED with its bug fixed: colsum
//    ds_add_f32 into ssacc with per-wave k-rotation (wave w handles column
//    block (k+2w)&31) -> 16 waves hit disjoint addresses at all times; no
//    same-address serialization (round-3's 16-way pileup). LDS 49.3 KB,
//    no ssp[32] -> low VGPR, 2 blocks/CU, 32 waves/CU.
//  - Scaled coordinates: coords staged premultiplied by a=sqrt(-l2c), so
//    s2 = -l2c*d2; exp2(-s2) uses the free neg modifier; l2p*d2 = -4*s2
//    (levels are exact ratio 4); sqrt constant 1/a folded into wcost.
//  - s=9 (l2c=0): colsum collapses to ss(m) = rn(m) * sum(fn) — no k-loop.
//  - s=10 (level 0): e = g exactly — no exp in the sweep at all.
__global__ __launch_bounds__(THREADS, 2) void fused_step(
        const float* __restrict__ xyz1, const float* __restrict__ xyz2,
        float* __restrict__ rLb, float* __restrict__ fb,
        const float* __restrict__ rRp,   // rR(s-1) in   (unused if !has_p2)
        float* __restrict__ rRn_g,       // rR(s)  out   (designated block)
        const float* __restrict__ ssp_g, // ss(s-1) in   (unused if !has_p2)
        float* __restrict__ ssc_g,       // ss(s) atomic accumulate (pre-zeroed)
        float* __restrict__ ssz_g,       // ss(s+1) zeroed here for next kernel
        float* __restrict__ out,
        float ascale, float inva, int has_p2, int has_p1, int pow4, int lcz)
{
    // raw[0:8192)      : sp    = float4 (a*x, a*y, a*z, rn)  32 KB
    // raw[8192:10240)  : sg    = g                            8 KB
    // raw[10240:12288) : ssacc = ss accumulator               8 KB
    // raw[12288:..)    : wcost[16], sfn_l[16]
    __shared__ __align__(16) float raw[6 * M_ + 2 * WAVES];
    float4* sp    = (float4*)raw;
    float*  sg    = raw + 4 * M_;
    float*  ssacc = raw + 5 * M_;
    float*  wcost = raw + 6 * M_;
    float*  sfn_l = raw + 6 * M_ + WAVES;

    const int b   = blockIdx.x / BPB;
    const int blk = blockIdx.x % BPB;
    const int n0  = blk * RPB;
    const int tid = threadIdx.x;
    const bool designated = (blk == 0);

    // ---- staging: scaled points + per-column factors ----
    const float* x2 = xyz2 + (size_t)b * M_ * 3;
    for (int m = tid; m < M_; m += THREADS) {
        const float x = x2[3*m] * ascale, y = x2[3*m+1] * ascale,
                    z = x2[3*m+2] * ascale;
        float g = 0.f, rn = 1.f;
        if (has_p2) {
            const float rr = rRp[b * M_ + m];
            const float sv = ssp_g[b * M_ + m];
            const float ratio = fminf(rr / (sv + EPS), 1.f);
            g  = rr * ratio;
            rn = fmaxf(rr - sv * ratio, 0.f);
        }
        sp[m] = make_float4(x, y, z, rn);
        sg[m] = g;
        ssacc[m] = 0.f;
        if (designated) {
            if (has_p1) rRn_g[b * M_ + m] = rn;
            ssz_g[b * M_ + m] = 0.f;
        }
    }
    __syncthreads();

    const int wave = tid >> 6, lane = tid & 63;
    const int nw = n0 + wave * RPW;

    float xv[RPW], yv[RPW], zv[RPW];
    #pragma unroll
    for (int r = 0; r < RPW; ++r) {
        const float* q = xyz1 + (size_t)(b * N_ + nw + r) * 3;
        xv[r] = q[0] * ascale; yv[r] = q[1] * ascale; zv[r] = q[2] * ascale;
    }

    float accd[RPW], accc[RPW], p[RPW];
    #pragma unroll
    for (int r = 0; r < RPW; ++r) { accd[r] = 0.f; accc[r] = 0.f; p[r] = 0.f; }

    // ---- fused sweep: phase2(s-1) + rowsum(s) on scaled coords ----
    if (has_p2 && has_p1 && pow4) {
        // s=1..8: ep = exp2(-4*s2) == exp2(l2p*d2); ec = exp2(-s2) == exp2(l2c*d2)
        #pragma unroll
        for (int k = 0; k < 32; ++k) {
            const float4 c = sp[lane + (k << 6)];
            const float  g = sg[lane + (k << 6)];
            #pragma unroll
            for (int r = 0; r < RPW; ++r) {
                const float dx = xv[r]-c.x, dy = yv[r]-c.y, dz = zv[r]-c.z;
                const float s2 = dx*dx + dy*dy + dz*dz;
                const float ec = __builtin_amdgcn_exp2f(-s2);
                const float e  = __builtin_amdgcn_exp2f(-4.f * s2) * g;
                accd[r] += e;
                accc[r] += e * __builtin_amdgcn_sqrtf(s2);
                p[r] += ec * c.w;
            }
        }
    } else if (has_p2 && has_p1) {
        // s=9: scale from l2p; l2c == 0 -> p-term is just rn
        #pragma unroll
        for (int k = 0; k < 32; ++k) {
            const float4 c = sp[lane + (k << 6)];
            const float  g = sg[lane + (k << 6)];
            #pragma unroll
            for (int r = 0; r < RPW; ++r) {
                const float dx = xv[r]-c.x, dy = yv[r]-c.y, dz = zv[r]-c.z;
                const float s2 = dx*dx + dy*dy + dz*dz;
                const float e  = __builtin_amdgcn_exp2f(-s2) * g;
                accd[r] += e;
                accc[r] += e * __builtin_amdgcn_sqrtf(s2);
                p[r] += c.w;
            }
        }
    } else if (has_p1) {
        // s=0: p-only
        #pragma unroll
        for (int k = 0; k < 32; ++k) {
            const float4 c = sp[lane + (k << 6)];
            #pragma unroll
            for (int r = 0; r < RPW; ++r) {
                const float dx = xv[r]-c.x, dy = yv[r]-c.y, dz = zv[r]-c.z;
                const float s2 = dx*dx + dy*dy + dz*dz;
                p[r] += __builtin_amdgcn_exp2f(-s2) * c.w;
            }
        }
    } else {
        // s=10: phase2 level is 0 -> e = g exactly; ascale = 1 so s2 = d2
        #pragma unroll
        for (int k = 0; k < 32; ++k) {
            const float4 c = sp[lane + (k << 6)];
            const float  g = sg[lane + (k << 6)];
            #pragma unroll
            for (int r = 0; r < RPW; ++r) {
                const float dx = xv[r]-c.x, dy = yv[r]-c.y, dz = zv[r]-c.z;
                const float s2 = dx*dx + dy*dy + dz*dz;
                accd[r] += g;
                accc[r] += g * __builtin_amdgcn_sqrtf(s2);
            }
        }
    }

    // ---- wave reductions (rows are wave-private) ----
    if (has_p2) {
        #pragma unroll
        for (int r = 0; r < RPW; ++r) {
            #pragma unroll
            for (int off = 32; off >= 1; off >>= 1) {
                accd[r] += __shfl_xor(accd[r], off, 64);
                accc[r] += __shfl_xor(accc[r], off, 64);
            }
        }
    }
    if (has_p1) {
        #pragma unroll
        for (int r = 0; r < RPW; ++r) {
            #pragma unroll
            for (int off = 32; off >= 1; off >>= 1)
                p[r] += __shfl_xor(p[r], off, 64);
        }
    }

    float rl_new[RPW];
    float cw = 0.f;
    if (has_p2) {
        #pragma unroll
        for (int r = 0; r < RPW; ++r) {
            const int idx = b * N_ + nw + r;
            const float fo = fb[idx];               // f(s-1), broadcast load
            const float rl = rLb[idx];
            rl_new[r] = fmaxf(rl - fo * accd[r], 0.f);
            cw += fo * accc[r];
        }
    } else {
        #pragma unroll
        for (int r = 0; r < RPW; ++r) rl_new[r] = 1.f;
    }
    if (lane == 0) wcost[wave] = cw * inva;   // fold 1/a from sqrt(s2)=a*sqrt(d2)

    // ---- phase1 colsums ----
    if (has_p1) {
        float fn[RPW];
        #pragma unroll
        for (int r = 0; r < RPW; ++r)
            fn[r] = rl_new[r] / (p[r] + EPS);
        if (lane == 0) {
            #pragma unroll
            for (int r = 0; r < RPW; ++r) {
                const int idx = b * N_ + nw + r;
                fb[idx]  = fn[r];
                rLb[idx] = rl_new[r];
            }
        }
        if (!lcz) {
            // rotated ds_add colsum: wave w handles column block (k+2w)&31 ->
            // disjoint addresses across the 16 waves at all times.
            #pragma unroll
            for (int k = 0; k < 32; ++k) {
                const int kk = ((k + (wave << 1)) & 31) << 6;
                const float4 c = sp[lane + kk];
                float s = 0.f;
                #pragma unroll
                for (int r = 0; r < RPW; ++r) {
                    const float dx = xv[r]-c.x, dy = yv[r]-c.y, dz = zv[r]-c.z;
                    const float s2 = dx*dx + dy*dy + dz*dz;
                    s += __builtin_amdgcn_exp2f(-s2) * fn[r];
                }
                atomicAdd(&ssacc[lane + kk], s * c.w);
            }
        } else {
            // s=9: l2c == 0 -> e == 1 -> ss(m) = rn(m) * sum_block(fn)
            if (lane == 0) sfn_l[wave] = fn[0] + fn[1];
        }
        __syncthreads();   // ssacc / sfn_l complete; wcost visible
        if (tid == 0 && has_p2) {
            float t = 0.f;
            #pragma unroll
            for (int w = 0; w < WAVES; ++w) t += wcost[w];
            atomicAdd(&out[b], t);
        }
        if (!lcz) {
            for (int m = tid; m < M_; m += THREADS)
                atomicAdd(&ssc_g[b * M_ + m], ssacc[m]);
        } else {
            float tot = 0.f;
            #pragma unroll
            for (int w = 0; w < WAVES; ++w) tot += sfn_l[w];
            for (int m = tid; m < M_; m += THREADS)
                atomicAdd(&ssc_g[b * M_ + m], sp[m].w * tot);
        }
    } else {
        __syncthreads();   // wcost visible
        if (tid == 0) {
            float t = 0.f;
            #pragma unroll
            for (int w = 0; w < WAVES; ++w) t += wcost[w];
            atomicAdd(&out[b], t);
        }
    }
}

extern "C" void kernel_launch(void* const* d_in, const int* in_sizes, int n_in,
                              void* d_out, int out_size, void* d_ws, size_t ws_size,
                              hipStream_t stream) {
    const float* xyz1 = (const float*)d_in[0];
    const float* xyz2 = (const float*)d_in[1];
    float* out = (float*)d_out;
    float* ws = (float*)d_ws;
    const int SZ = B_ * N_;          // == B_*M_ == 16384
    float* rL  = ws;
    float* fb  = ws + SZ;
    float* rRb[2] = { ws + 2*SZ, ws + 3*SZ };
    float* ssb[3] = { ws + 4*SZ, ws + 5*SZ, ws + 6*SZ };

    init_kernel<<<(SZ + 255) / 256, 256, 0, stream>>>(rL, fb, ssb[0], out);

    constexpr float LOG2E = 1.4426950408889634f;
    static const float levels[10] = {
        -16384.f, -4096.f, -1024.f, -256.f, -64.f,
        -16.f, -4.f, -1.f, -0.25f, 0.f
    };
    // kernel s (s=0..10): phase2 of step s-1 (if s>0) + phase1 of step s (if s<10)
    for (int s = 0; s <= 10; ++s) {
        const int has_p2 = (s > 0);
        const int has_p1 = (s < 10);
        const int pow4   = (s >= 1 && s <= 8);   // levels[s-1] == 4*levels[s]
        const int lcz    = (s == 9);             // l2c == 0
        // coordinate scale: a^2 = -l2c for s<=8; -l2p for s=9; 1 for s=10
        const float lvl = (s <= 8) ? levels[s] : levels[8];
        const float ascale = (s == 10) ? 1.f : sqrtf(-(lvl * LOG2E));
        const float inva   = 1.f / ascale;
        fused_step<<<GRID, THREADS, 0, stream>>>(
            xyz1, xyz2, rL, fb,
            rRb[(s + 1) & 1],      // rR(s-1)   (s>=1; unused at s=0)
            rRb[s & 1],            // rR(s) out
            ssb[(s + 2) % 3],      // ss(s-1)   (s>=1; unused at s=0)
            ssb[s % 3],            // ss(s) accumulate (pre-zeroed by kernel s-1 / init)
            ssb[(s + 1) % 3],      // ss(s+1) zeroed for next kernel
            out, ascale, inva, has_p2, has_p1, pow4, lcz);
    }
}

// Round 7
// 497.238 us; speedup vs baseline: 2.0540x; 2.0540x over previous
//
#include <hip/hip_runtime.h>
#include <math.h>

#define EPS 1e-9f

constexpr int B_ = 8, N_ = 2048, M_ = 2048;
constexpr int THREADS = 512;               // 8 waves/block (round-2 proven skeleton)
constexpr int WAVES = 8;
constexpr int RPW = 4;                     // rows per wave (wave-uniform rows!)
constexpr int RPB = WAVES * RPW;           // 32 rows per block
constexpr int BPB = N_ / RPB;              // 64 blocks per batch
constexpr int GRID = B_ * BPB;             // 512 blocks = 2/CU

__global__ __launch_bounds__(256) void init_kernel(float* rL, float* fb,
                                                   float* ss0, float* out) {
    int i = blockIdx.x * blockDim.x + threadIdx.x;
    if (i < B_ * N_) { rL[i] = 1.f; fb[i] = 0.f; ss0[i] = 0.f; }
    if (i < B_) out[i] = 0.f;
}

// One block per batch: bitonic sort of 2048 points by x (payload y,z), plus
// per-64-point-block x-bounds. One-time cost; enables exact underflow skipping
// (all downstream state is kept in sorted index space; outputs are
// permutation-invariant per-batch scalars).
__global__ __launch_bounds__(1024) void sort_kernel(
        const float* __restrict__ xyz, float4* __restrict__ outp,
        float2* __restrict__ bounds) {
    __shared__ float4 buf[2048];
    const int b = blockIdx.x, t = threadIdx.x;
    for (int i = t; i < 2048; i += 1024) {
        const float* q = xyz + ((size_t)b * 2048 + i) * 3;
        buf[i] = make_float4(q[0], q[1], q[2], 0.f);
    }
    __syncthreads();
    for (int ksz = 2; ksz <= 2048; ksz <<= 1) {
        for (int j = ksz >> 1; j >= 1; j >>= 1) {
            const int i  = t + (t & ~(j - 1));
            const int pr = i + j;
            const bool up = ((i & ksz) == 0);
            const float4 A = buf[i], Bv = buf[pr];
            if ((A.x > Bv.x) == up) { buf[i] = Bv; buf[pr] = A; }
            __syncthreads();
        }
    }
    for (int i = t; i < 2048; i += 1024)
        outp[(size_t)b * 2048 + i] = buf[i];
    if (bounds != nullptr && t < 32)
        bounds[b * 32 + t] = make_float2(buf[t * 64].x, buf[t * 64 + 63].x);
}

// Fused step s: [phase2 of s-1] + [phase1 of s] sharing one d2 sweep, on
// SORTED points with per-(wave, k-block) exact underflow skipping:
//   skip-all  iff min-possible s2 > 160  (exp2(-s2) == 0 exactly; 2^-160 < min denormal)
//   p-only    iff 4*min s2 > 160        (exp2(-4*s2) == 0 exactly; levels ratio-4)
// Bound: rows are wave-uniform; columns of k-block are sorted-consecutive with
// staged x in [lo,hi] (rounding-monotone scaling preserves the bound). Skipped
// contributions are fp32-exact zeros -> bit-identical results.
__global__ __launch_bounds__(THREADS, 2) void fused_step(
        const float4* __restrict__ xyz1s, const float4* __restrict__ xyz2s,
        const float2* __restrict__ bounds2,
        float* __restrict__ rLb, float* __restrict__ fb,
        const float* __restrict__ rRp,   // rR(s-1) in   (unused if !has_p2)
        float* __restrict__ rRn_g,       // rR(s)  out   (designated block)
        const float* __restrict__ ssp_g, // ss(s-1) in   (unused if !has_p2)
        float* __restrict__ ssc_g,       // ss(s) atomic accumulate (pre-zeroed)
        float* __restrict__ ssz_g,       // ss(s+1) zeroed here for next kernel
        float* __restrict__ out,
        float ascale, float inva, int has_p2, int has_p1, int domask, int lcz)
{
    // raw[0:8192)      : sp  = float4 (a*x,a*y,a*z,rn)  32 KB
    // raw[8192:10240)  : sg  = g                         8 KB
    // raw[0:16384)     : ssl overlay (8 waves x 2048)   64 KB after barrier
    // raw[16384:..)    : wcost[8], sfn_l[8], bnds[32] (outside overlay)
    __shared__ __align__(16) float raw[8 * M_ + 2 * WAVES + 64];
    float4* sp    = (float4*)raw;
    float*  sg    = raw + 4 * M_;
    float*  ssl   = raw;
    float*  wcost = raw + 8 * M_;
    float*  sfn_l = raw + 8 * M_ + WAVES;
    float2* bnds  = (float2*)(raw + 8 * M_ + 2 * WAVES);

    const int b   = blockIdx.x / BPB;
    const int blk = blockIdx.x % BPB;
    const int n0  = blk * RPB;
    const int tid = threadIdx.x;
    const bool designated = (blk == 0);

    // ---- staging: scaled sorted points + per-column factors ----
    for (int m = tid; m < M_; m += THREADS) {
        const float4 q = xyz2s[b * M_ + m];
        float g = 0.f, rn = 1.f;
        if (has_p2) {
            const float rr = rRp[b * M_ + m];
            const float sv = ssp_g[b * M_ + m];
            const float ratio = fminf(rr / (sv + EPS), 1.f);
            g  = rr * ratio;
            rn = fmaxf(rr - sv * ratio, 0.f);
        }
        sp[m] = make_float4(q.x * ascale, q.y * ascale, q.z * ascale, rn);
        sg[m] = g;
        if (designated) {
            if (has_p1) rRn_g[b * M_ + m] = rn;
            ssz_g[b * M_ + m] = 0.f;
        }
    }
    if (tid < 32) {
        const float2 bb = bounds2[b * 32 + tid];
        bnds[tid] = make_float2(bb.x * ascale, bb.y * ascale);
    }
    __syncthreads();

    const int wave = tid >> 6, lane = tid & 63;
    const int nw = n0 + wave * RPW;

    float xv[RPW], yv[RPW], zv[RPW];
    #pragma unroll
    for (int r = 0; r < RPW; ++r) {
        const float4 q = xyz1s[b * N_ + nw + r];
        xv[r] = q.x * ascale; yv[r] = q.y * ascale; zv[r] = q.z * ascale;
    }

    // ---- per-(wave, k-block) skip masks (wave-uniform) ----
    unsigned mf = 0xffffffffu, mp = 0u;
    if (domask) {
        mf = 0u;
        for (int k = 0; k < 32; ++k) {
            const float2 bb = bnds[k];
            float t2 = 1e30f;
            #pragma unroll
            for (int r = 0; r < RPW; ++r) {
                const float t = fmaxf(fmaxf(bb.x - xv[r], xv[r] - bb.y), 0.f);
                t2 = fminf(t2, t * t);
            }
            if (t2 * 4.f <= 160.f)  mf |= (1u << k);   // phase2 exp may be alive
            else if (t2 <= 160.f)   mp |= (1u << k);   // only p exp alive
        }
    }
    const unsigned alive = mf | mp;

    float accd[RPW], accc[RPW], p[RPW];
    #pragma unroll
    for (int r = 0; r < RPW; ++r) { accd[r] = 0.f; accc[r] = 0.f; p[r] = 0.f; }

    // ---- fused sweep ----
    if (has_p2 && has_p1 && domask) {
        // s=1..8: ep = exp2(-4*s2) (levels ratio-4), ec = exp2(-s2)
        for (int k = 0; k < 32; ++k) {
            if (!((alive >> k) & 1u)) continue;
            const int kk = (k << 6) + lane;
            const float4 c = sp[kk];
            if ((mf >> k) & 1u) {
                const float g = sg[kk];
                #pragma unroll
                for (int r = 0; r < RPW; ++r) {
                    const float dx = xv[r]-c.x, dy = yv[r]-c.y, dz = zv[r]-c.z;
                    const float s2 = dx*dx + dy*dy + dz*dz;
                    const float ec = __builtin_amdgcn_exp2f(-s2);
                    const float e  = __builtin_amdgcn_exp2f(-4.f * s2) * g;
                    accd[r] += e;
                    accc[r] += e * __builtin_amdgcn_sqrtf(s2);
                    p[r] += ec * c.w;
                }
            } else {
                #pragma unroll
                for (int r = 0; r < RPW; ++r) {
                    const float dx = xv[r]-c.x, dy = yv[r]-c.y, dz = zv[r]-c.z;
                    const float s2 = dx*dx + dy*dy + dz*dz;
                    p[r] += __builtin_amdgcn_exp2f(-s2) * c.w;
                }
            }
        }
    } else if (!has_p2) {
        // s=0: p-only
        for (int k = 0; k < 32; ++k) {
            if (!((alive >> k) & 1u)) continue;
            const int kk = (k << 6) + lane;
            const float4 c = sp[kk];
            #pragma unroll
            for (int r = 0; r < RPW; ++r) {
                const float dx = xv[r]-c.x, dy = yv[r]-c.y, dz = zv[r]-c.z;
                const float s2 = dx*dx + dy*dy + dz*dz;
                p[r] += __builtin_amdgcn_exp2f(-s2) * c.w;
            }
        }
    } else if (has_p1) {
        // s=9: a^2 from l2p; l2c == 0 -> p-term is rn; no skipping possible
        for (int k = 0; k < 32; ++k) {
            const int kk = (k << 6) + lane;
            const float4 c = sp[kk];
            const float  g = sg[kk];
            #pragma unroll
            for (int r = 0; r < RPW; ++r) {
                const float dx = xv[r]-c.x, dy = yv[r]-c.y, dz = zv[r]-c.z;
                const float s2 = dx*dx + dy*dy + dz*dz;
                const float e  = __builtin_amdgcn_exp2f(-s2) * g;
                accd[r] += e;
                accc[r] += e * __builtin_amdgcn_sqrtf(s2);
                p[r] += c.w;
            }
        }
    } else {
        // s=10: phase2 level 0 -> e = g exactly (ascale = 1)
        for (int k = 0; k < 32; ++k) {
            const int kk = (k << 6) + lane;
            const float4 c = sp[kk];
            const float  g = sg[kk];
            #pragma unroll
            for (int r = 0; r < RPW; ++r) {
                const float dx = xv[r]-c.x, dy = yv[r]-c.y, dz = zv[r]-c.z;
                const float s2 = dx*dx + dy*dy + dz*dz;
                accd[r] += g;
                accc[r] += g * __builtin_amdgcn_sqrtf(s2);
            }
        }
    }

    // ---- wave reductions (rows are wave-private) ----
    if (has_p2) {
        #pragma unroll
        for (int r = 0; r < RPW; ++r) {
            #pragma unroll
            for (int off = 32; off >= 1; off >>= 1) {
                accd[r] += __shfl_xor(accd[r], off, 64);
                accc[r] += __shfl_xor(accc[r], off, 64);
            }
        }
    }
    if (has_p1) {
        #pragma unroll
        for (int r = 0; r < RPW; ++r) {
            #pragma unroll
            for (int off = 32; off >= 1; off >>= 1)
                p[r] += __shfl_xor(p[r], off, 64);
        }
    }

    float rl_new[RPW];
    float cw = 0.f;
    if (has_p2) {
        #pragma unroll
        for (int r = 0; r < RPW; ++r) {
            const int idx = b * N_ + nw + r;
            const float fo = fb[idx];               // f(s-1), broadcast load
            const float rl = rLb[idx];
            rl_new[r] = fmaxf(rl - fo * accd[r], 0.f);
            cw += fo * accc[r];
        }
    } else {
        #pragma unroll
        for (int r = 0; r < RPW; ++r) rl_new[r] = 1.f;
    }
    if (lane == 0) wcost[wave] = cw * inva;  // fold 1/a: sqrt(s2) = a*sqrt(d2)

    // ---- phase1 colsums ----
    if (has_p1) {
        float fn[RPW];
        #pragma unroll
        for (int r = 0; r < RPW; ++r)
            fn[r] = rl_new[r] / (p[r] + EPS);
        if (lane == 0) {
            #pragma unroll
            for (int r = 0; r < RPW; ++r) {
                const int idx = b * N_ + nw + r;
                fb[idx]  = fn[r];
                rLb[idx] = rl_new[r];
            }
        }
        if (!lcz) {
            float ssp[32];
            for (int k = 0; k < 32; ++k) {
                float sv = 0.f;
                if ((alive >> k) & 1u) {
                    const int kk = (k << 6) + lane;
                    const float4 c = sp[kk];
                    float acc = 0.f;
                    #pragma unroll
                    for (int r = 0; r < RPW; ++r) {
                        const float dx = xv[r]-c.x, dy = yv[r]-c.y, dz = zv[r]-c.z;
                        const float s2 = dx*dx + dy*dy + dz*dz;
                        acc += __builtin_amdgcn_exp2f(-s2) * fn[r];
                    }
                    sv = acc * c.w;
                }
                ssp[k] = sv;
            }
            __syncthreads();   // all sp/sg reads done -> ssl overlay safe
            #pragma unroll
            for (int k = 0; k < 32; ++k)
                ssl[wave * M_ + (k << 6) + lane] = ssp[k];
            __syncthreads();
            if (tid == 0 && has_p2) {
                float t = 0.f;
                #pragma unroll
                for (int w = 0; w < WAVES; ++w) t += wcost[w];
                atomicAdd(&out[b], t);
            }
            for (int m = tid; m < M_; m += THREADS) {
                const float sval = ssl[m]        + ssl[M_ + m]   + ssl[2*M_ + m]
                                 + ssl[3*M_ + m] + ssl[4*M_ + m] + ssl[5*M_ + m]
                                 + ssl[6*M_ + m] + ssl[7*M_ + m];
                if (sval != 0.f) atomicAdd(&ssc_g[b * M_ + m], sval);
            }
        } else {
            // s=9: l2c == 0 -> ec == 1 -> ss(m) = rn(m) * sum_block(fn)
            if (lane == 0) sfn_l[wave] = fn[0] + fn[1] + fn[2] + fn[3];
            __syncthreads();
            if (tid == 0 && has_p2) {
                float t = 0.f;
                #pragma unroll
                for (int w = 0; w < WAVES; ++w) t += wcost[w];
                atomicAdd(&out[b], t);
            }
            float tot = 0.f;
            #pragma unroll
            for (int w = 0; w < WAVES; ++w) tot += sfn_l[w];
            for (int m = tid; m < M_; m += THREADS) {
                const float v = sp[m].w * tot;
                if (v != 0.f) atomicAdd(&ssc_g[b * M_ + m], v);
            }
        }
    } else {
        __syncthreads();   // wcost visible
        if (tid == 0) {
            float t = 0.f;
            #pragma unroll
            for (int w = 0; w < WAVES; ++w) t += wcost[w];
            atomicAdd(&out[b], t);
        }
    }
}

extern "C" void kernel_launch(void* const* d_in, const int* in_sizes, int n_in,
                              void* d_out, int out_size, void* d_ws, size_t ws_size,
                              hipStream_t stream) {
    const float* xyz1 = (const float*)d_in[0];
    const float* xyz2 = (const float*)d_in[1];
    float* out = (float*)d_out;
    float* ws = (float*)d_ws;
    const int SZ = B_ * N_;          // == B_*M_ == 16384
    float* rL  = ws;
    float* fb  = ws + SZ;
    float* rRb[2] = { ws + 2*SZ, ws + 3*SZ };
    float* ssb[3] = { ws + 4*SZ, ws + 5*SZ, ws + 6*SZ };
    float2* bounds2 = (float2*)(ws + 7*SZ);            // 8*32 float2 = 512 floats
    float4* xyz1s   = (float4*)(ws + 7*SZ + 512);      // 16B-aligned (offset 460800B)
    float4* xyz2s   = xyz1s + (size_t)B_ * N_;
    // workspace footprint: 7*SZ + 512 + 2*16384*4 floats ≈ 985 KB

    init_kernel<<<(SZ + 255) / 256, 256, 0, stream>>>(rL, fb, ssb[0], out);
    sort_kernel<<<B_, 1024, 0, stream>>>(xyz1, xyz1s, nullptr);
    sort_kernel<<<B_, 1024, 0, stream>>>(xyz2, xyz2s, bounds2);

    constexpr float LOG2E = 1.4426950408889634f;
    static const float levels[10] = {
        -16384.f, -4096.f, -1024.f, -256.f, -64.f,
        -16.f, -4.f, -1.f, -0.25f, 0.f
    };
    // kernel s (s=0..10): phase2 of step s-1 (if s>0) + phase1 of step s (if s<10)
    for (int s = 0; s <= 10; ++s) {
        const int has_p2 = (s > 0);
        const int has_p1 = (s < 10);
        const int domask = (s <= 8);             // masks valid (level finite)
        const int lcz    = (s == 9);             // l2c == 0
        const float lvl  = (s <= 8) ? levels[s] : levels[8];
        const float ascale = (s == 10) ? 1.f : sqrtf(-(lvl * LOG2E));
        const float inva   = 1.f / ascale;
        fused_step<<<GRID, THREADS, 0, stream>>>(
            xyz1s, xyz2s, bounds2, rL, fb,
            rRb[(s + 1) & 1],      // rR(s-1)   (s>=1; unused at s=0)
            rRb[s & 1],            // rR(s) out
            ssb[(s + 2) % 3],      // ss(s-1)   (s>=1; unused at s=0)
            ssb[s % 3],            // ss(s) accumulate (pre-zeroed by kernel s-1 / init)
            ssb[(s + 1) % 3],      // ss(s+1) zeroed for next kernel
            out, ascale, inva, has_p2, has_p1, domask, lcz);
    }
}

// Round 8
// 366.035 us; speedup vs baseline: 2.7902x; 1.3584x over previous
//
#include <hip/hip_runtime.h>
#include <math.h>

#define EPS 1e-9f

constexpr int B_ = 8, N_ = 2048, M_ = 2048;
constexpr int THREADS = 512;               // 8 waves/block (round-2 proven skeleton)
constexpr int WAVES = 8;
constexpr int RPW = 4;                     // rows per wave (wave-uniform rows!)
constexpr int RPB = WAVES * RPW;           // 32 rows per block
constexpr int BPB = N_ / RPB;              // 64 blocks per batch
constexpr int GRID = B_ * BPB;             // 512 blocks = 2/CU

__global__ __launch_bounds__(256) void init_kernel(float* rL, float* fb,
                                                   float* ss0, float* out) {
    int i = blockIdx.x * blockDim.x + threadIdx.x;
    if (i < B_ * N_) { rL[i] = 1.f; fb[i] = 0.f; ss0[i] = 0.f; }
    if (i < B_) out[i] = 0.f;
}

// Merged sort: grid = 16 blocks — block bb<8 sorts xyz1 batch bb, bb>=8 sorts
// xyz2 batch bb-8 (+ per-64-block bounds). Key+index bitonic in LDS (16 KB);
// payload gathered once at the end. Phases with j<=64 are WAVE-LOCAL (pair
// elements live inside one wave's 128-elem window): no __syncthreads needed,
// only a compiler reorder fence. Full barriers only when a phase with j>=128
// is involved: 15 barriers instead of 66 (was 76.6us/dispatch x2 = 153us,
// pure barrier latency on an 8-block grid).
__global__ __launch_bounds__(1024) void sort_kernel(
        const float* __restrict__ xyz1, const float* __restrict__ xyz2,
        float4* __restrict__ out1, float4* __restrict__ out2,
        float2* __restrict__ bounds) {
    __shared__ float kx[2048];
    __shared__ int   ki[2048];
    const int bb = blockIdx.x;
    const bool isB = (bb >= B_);
    const int b = isB ? bb - B_ : bb;
    const float* __restrict__ src = isB ? xyz2 : xyz1;
    float4* __restrict__ dst = isB ? out2 : out1;
    const int t = threadIdx.x;

    for (int i = t; i < 2048; i += 1024) {
        kx[i] = src[((size_t)b * 2048 + i) * 3];
        ki[i] = i;
    }
    __syncthreads();

    bool prev_cross = false;
    for (int ksz = 2; ksz <= 2048; ksz <<= 1) {
        for (int j = ksz >> 1; j >= 1; j >>= 1) {
            const bool cross = (j >= 128);
            if (cross || prev_cross) __syncthreads();
            else __builtin_amdgcn_wave_barrier();
            const int i  = t + (t & ~(j - 1));
            const int pr = i + j;
            const bool up = ((i & ksz) == 0);
            const float ax = kx[i], bx = kx[pr];
            if ((ax > bx) == up) {
                const int ai = ki[i], bi = ki[pr];
                kx[i] = bx; kx[pr] = ax;
                ki[i] = bi; ki[pr] = ai;
            }
            prev_cross = cross;
        }
    }
    __syncthreads();

    for (int i = t; i < 2048; i += 1024) {
        const float* q = src + ((size_t)b * 2048 + ki[i]) * 3;
        dst[(size_t)b * 2048 + i] = make_float4(q[0], q[1], q[2], 0.f);
    }
    if (isB && t < 32)
        bounds[b * 32 + t] = make_float2(kx[t * 64], kx[t * 64 + 63]);
}

// Fused step s: [phase2 of s-1] + [phase1 of s] sharing one d2 sweep, on
// SORTED points with per-(wave, k-block) exact underflow skipping:
//   skip-all  iff min-possible s2 > 160  (exp2(-s2) == 0 exactly; 2^-160 < min denormal)
//   p-only    iff 4*min s2 > 160        (exp2(-4*s2) == 0 exactly; levels ratio-4)
// Bound: rows are wave-uniform; columns of k-block are sorted-consecutive with
// staged x in [lo,hi] (rounding-monotone scaling preserves the bound). Skipped
// contributions are fp32-exact zeros -> bit-identical results.
__global__ __launch_bounds__(THREADS, 2) void fused_step(
        const float4* __restrict__ xyz1s, const float4* __restrict__ xyz2s,
        const float2* __restrict__ bounds2,
        float* __restrict__ rLb, float* __restrict__ fb,
        const float* __restrict__ rRp,   // rR(s-1) in   (unused if !has_p2)
        float* __restrict__ rRn_g,       // rR(s)  out   (designated block)
        const float* __restrict__ ssp_g, // ss(s-1) in   (unused if !has_p2)
        float* __restrict__ ssc_g,       // ss(s) atomic accumulate (pre-zeroed)
        float* __restrict__ ssz_g,       // ss(s+1) zeroed here for next kernel
        float* __restrict__ out,
        float ascale, float inva, int has_p2, int has_p1, int domask, int lcz)
{
    // raw[0:8192)      : sp  = float4 (a*x,a*y,a*z,rn)  32 KB
    // raw[8192:10240)  : sg  = g                         8 KB
    // raw[0:16384)     : ssl overlay (8 waves x 2048)   64 KB after barrier
    // raw[16384:..)    : wcost[8], sfn_l[8], bnds[32] (outside overlay)
    __shared__ __align__(16) float raw[8 * M_ + 2 * WAVES + 64];
    float4* sp    = (float4*)raw;
    float*  sg    = raw + 4 * M_;
    float*  ssl   = raw;
    float*  wcost = raw + 8 * M_;
    float*  sfn_l = raw + 8 * M_ + WAVES;
    float2* bnds  = (float2*)(raw + 8 * M_ + 2 * WAVES);

    const int b   = blockIdx.x / BPB;
    const int blk = blockIdx.x % BPB;
    const int n0  = blk * RPB;
    const int tid = threadIdx.x;
    const bool designated = (blk == 0);

    // ---- staging: scaled sorted points + per-column factors ----
    for (int m = tid; m < M_; m += THREADS) {
        const float4 q = xyz2s[b * M_ + m];
        float g = 0.f, rn = 1.f;
        if (has_p2) {
            const float rr = rRp[b * M_ + m];
            const float sv = ssp_g[b * M_ + m];
            const float ratio = fminf(rr / (sv + EPS), 1.f);
            g  = rr * ratio;
            rn = fmaxf(rr - sv * ratio, 0.f);
        }
        sp[m] = make_float4(q.x * ascale, q.y * ascale, q.z * ascale, rn);
        sg[m] = g;
        if (designated) {
            if (has_p1) rRn_g[b * M_ + m] = rn;
            ssz_g[b * M_ + m] = 0.f;
        }
    }
    if (tid < 32) {
        const float2 bb = bounds2[b * 32 + tid];
        bnds[tid] = make_float2(bb.x * ascale, bb.y * ascale);
    }
    __syncthreads();

    const int wave = tid >> 6, lane = tid & 63;
    const int nw = n0 + wave * RPW;

    float xv[RPW], yv[RPW], zv[RPW];
    #pragma unroll
    for (int r = 0; r < RPW; ++r) {
        const float4 q = xyz1s[b * N_ + nw + r];
        xv[r] = q.x * ascale; yv[r] = q.y * ascale; zv[r] = q.z * ascale;
    }

    // ---- per-(wave, k-block) skip masks (wave-uniform) ----
    unsigned mf = 0xffffffffu, mp = 0u;
    if (domask) {
        mf = 0u;
        for (int k = 0; k < 32; ++k) {
            const float2 bb = bnds[k];
            float t2 = 1e30f;
            #pragma unroll
            for (int r = 0; r < RPW; ++r) {
                const float t = fmaxf(fmaxf(bb.x - xv[r], xv[r] - bb.y), 0.f);
                t2 = fminf(t2, t * t);
            }
            if (t2 * 4.f <= 160.f)  mf |= (1u << k);   // phase2 exp may be alive
            else if (t2 <= 160.f)   mp |= (1u << k);   // only p exp alive
        }
    }
    const unsigned alive = mf | mp;

    float accd[RPW], accc[RPW], p[RPW];
    #pragma unroll
    for (int r = 0; r < RPW; ++r) { accd[r] = 0.f; accc[r] = 0.f; p[r] = 0.f; }

    // ---- fused sweep ----
    if (has_p2 && has_p1 && domask) {
        // s=1..8: ep = exp2(-4*s2) (levels ratio-4), ec = exp2(-s2)
        for (int k = 0; k < 32; ++k) {
            if (!((alive >> k) & 1u)) continue;
            const int kk = (k << 6) + lane;
            const float4 c = sp[kk];
            if ((mf >> k) & 1u) {
                const float g = sg[kk];
                #pragma unroll
                for (int r = 0; r < RPW; ++r) {
                    const float dx = xv[r]-c.x, dy = yv[r]-c.y, dz = zv[r]-c.z;
                    const float s2 = dx*dx + dy*dy + dz*dz;
                    const float ec = __builtin_amdgcn_exp2f(-s2);
                    const float e  = __builtin_amdgcn_exp2f(-4.f * s2) * g;
                    accd[r] += e;
                    accc[r] += e * __builtin_amdgcn_sqrtf(s2);
                    p[r] += ec * c.w;
                }
            } else {
                #pragma unroll
                for (int r = 0; r < RPW; ++r) {
                    const float dx = xv[r]-c.x, dy = yv[r]-c.y, dz = zv[r]-c.z;
                    const float s2 = dx*dx + dy*dy + dz*dz;
                    p[r] += __builtin_amdgcn_exp2f(-s2) * c.w;
                }
            }
        }
    } else if (!has_p2) {
        // s=0: p-only
        for (int k = 0; k < 32; ++k) {
            if (!((alive >> k) & 1u)) continue;
            const int kk = (k << 6) + lane;
            const float4 c = sp[kk];
            #pragma unroll
            for (int r = 0; r < RPW; ++r) {
                const float dx = xv[r]-c.x, dy = yv[r]-c.y, dz = zv[r]-c.z;
                const float s2 = dx*dx + dy*dy + dz*dz;
                p[r] += __builtin_amdgcn_exp2f(-s2) * c.w;
            }
        }
    } else if (has_p1) {
        // s=9: a^2 from l2p; l2c == 0 -> p-term is rn; no skipping possible
        for (int k = 0; k < 32; ++k) {
            const int kk = (k << 6) + lane;
            const float4 c = sp[kk];
            const float  g = sg[kk];
            #pragma unroll
            for (int r = 0; r < RPW; ++r) {
                const float dx = xv[r]-c.x, dy = yv[r]-c.y, dz = zv[r]-c.z;
                const float s2 = dx*dx + dy*dy + dz*dz;
                const float e  = __builtin_amdgcn_exp2f(-s2) * g;
                accd[r] += e;
                accc[r] += e * __builtin_amdgcn_sqrtf(s2);
                p[r] += c.w;
            }
        }
    } else {
        // s=10: phase2 level 0 -> e = g exactly (ascale = 1)
        for (int k = 0; k < 32; ++k) {
            const int kk = (k << 6) + lane;
            const float4 c = sp[kk];
            const float  g = sg[kk];
            #pragma unroll
            for (int r = 0; r < RPW; ++r) {
                const float dx = xv[r]-c.x, dy = yv[r]-c.y, dz = zv[r]-c.z;
                const float s2 = dx*dx + dy*dy + dz*dz;
                accd[r] += g;
                accc[r] += g * __builtin_amdgcn_sqrtf(s2);
            }
        }
    }

    // ---- wave reductions (rows are wave-private) ----
    if (has_p2) {
        #pragma unroll
        for (int r = 0; r < RPW; ++r) {
            #pragma unroll
            for (int off = 32; off >= 1; off >>= 1) {
                accd[r] += __shfl_xor(accd[r], off, 64);
                accc[r] += __shfl_xor(accc[r], off, 64);
            }
        }
    }
    if (has_p1) {
        #pragma unroll
        for (int r = 0; r < RPW; ++r) {
            #pragma unroll
            for (int off = 32; off >= 1; off >>= 1)
                p[r] += __shfl_xor(p[r], off, 64);
        }
    }

    float rl_new[RPW];
    float cw = 0.f;
    if (has_p2) {
        #pragma unroll
        for (int r = 0; r < RPW; ++r) {
            const int idx = b * N_ + nw + r;
            const float fo = fb[idx];               // f(s-1), broadcast load
            const float rl = rLb[idx];
            rl_new[r] = fmaxf(rl - fo * accd[r], 0.f);
            cw += fo * accc[r];
        }
    } else {
        #pragma unroll
        for (int r = 0; r < RPW; ++r) rl_new[r] = 1.f;
    }
    if (lane == 0) wcost[wave] = cw * inva;  // fold 1/a: sqrt(s2) = a*sqrt(d2)

    // ---- phase1 colsums ----
    if (has_p1) {
        float fn[RPW];
        #pragma unroll
        for (int r = 0; r < RPW; ++r)
            fn[r] = rl_new[r] / (p[r] + EPS);
        if (lane == 0) {
            #pragma unroll
            for (int r = 0; r < RPW; ++r) {
                const int idx = b * N_ + nw + r;
                fb[idx]  = fn[r];
                rLb[idx] = rl_new[r];
            }
        }
        if (!lcz) {
            float ssp[32];
            for (int k = 0; k < 32; ++k) {
                float sv = 0.f;
                if ((alive >> k) & 1u) {
                    const int kk = (k << 6) + lane;
                    const float4 c = sp[kk];
                    float acc = 0.f;
                    #pragma unroll
                    for (int r = 0; r < RPW; ++r) {
                        const float dx = xv[r]-c.x, dy = yv[r]-c.y, dz = zv[r]-c.z;
                        const float s2 = dx*dx + dy*dy + dz*dz;
                        acc += __builtin_amdgcn_exp2f(-s2) * fn[r];
                    }
                    sv = acc * c.w;
                }
                ssp[k] = sv;
            }
            __syncthreads();   // all sp/sg reads done -> ssl overlay safe
            #pragma unroll
            for (int k = 0; k < 32; ++k)
                ssl[wave * M_ + (k << 6) + lane] = ssp[k];
            __syncthreads();
            if (tid == 0 && has_p2) {
                float t = 0.f;
                #pragma unroll
                for (int w = 0; w < WAVES; ++w) t += wcost[w];
                atomicAdd(&out[b], t);
            }
            for (int m = tid; m < M_; m += THREADS) {
                const float sval = ssl[m]        + ssl[M_ + m]   + ssl[2*M_ + m]
                                 + ssl[3*M_ + m] + ssl[4*M_ + m] + ssl[5*M_ + m]
                                 + ssl[6*M_ + m] + ssl[7*M_ + m];
                if (sval != 0.f) atomicAdd(&ssc_g[b * M_ + m], sval);
            }
        } else {
            // s=9: l2c == 0 -> ec == 1 -> ss(m) = rn(m) * sum_block(fn)
            if (lane == 0) sfn_l[wave] = fn[0] + fn[1] + fn[2] + fn[3];
            __syncthreads();
            if (tid == 0 && has_p2) {
                float t = 0.f;
                #pragma unroll
                for (int w = 0; w < WAVES; ++w) t += wcost[w];
                atomicAdd(&out[b], t);
            }
            float tot = 0.f;
            #pragma unroll
            for (int w = 0; w < WAVES; ++w) tot += sfn_l[w];
            for (int m = tid; m < M_; m += THREADS) {
                const float v = sp[m].w * tot;
                if (v != 0.f) atomicAdd(&ssc_g[b * M_ + m], v);
            }
        }
    } else {
        __syncthreads();   // wcost visible
        if (tid == 0) {
            float t = 0.f;
            #pragma unroll
            for (int w = 0; w < WAVES; ++w) t += wcost[w];
            atomicAdd(&out[b], t);
        }
    }
}

extern "C" void kernel_launch(void* const* d_in, const int* in_sizes, int n_in,
                              void* d_out, int out_size, void* d_ws, size_t ws_size,
                              hipStream_t stream) {
    const float* xyz1 = (const float*)d_in[0];
    const float* xyz2 = (const float*)d_in[1];
    float* out = (float*)d_out;
    float* ws = (float*)d_ws;
    const int SZ = B_ * N_;          // == B_*M_ == 16384
    float* rL  = ws;
    float* fb  = ws + SZ;
    float* rRb[2] = { ws + 2*SZ, ws + 3*SZ };
    float* ssb[3] = { ws + 4*SZ, ws + 5*SZ, ws + 6*SZ };
    float2* bounds2 = (float2*)(ws + 7*SZ);            // 8*32 float2 = 512 floats
    float4* xyz1s   = (float4*)(ws + 7*SZ + 512);      // 16B-aligned (offset 460800B)
    float4* xyz2s   = xyz1s + (size_t)B_ * N_;
    // workspace footprint: 7*SZ + 512 + 2*16384*4 floats ≈ 985 KB

    init_kernel<<<(SZ + 255) / 256, 256, 0, stream>>>(rL, fb, ssb[0], out);
    sort_kernel<<<2 * B_, 1024, 0, stream>>>(xyz1, xyz2, xyz1s, xyz2s, bounds2);

    constexpr float LOG2E = 1.4426950408889634f;
    static const float levels[10] = {
        -16384.f, -4096.f, -1024.f, -256.f, -64.f,
        -16.f, -4.f, -1.f, -0.25f, 0.f
    };
    // kernel s (s=0..10): phase2 of step s-1 (if s>0) + phase1 of step s (if s<10)
    for (int s = 0; s <= 10; ++s) {
        const int has_p2 = (s > 0);
        const int has_p1 = (s < 10);
        const int domask = (s <= 8);             // masks valid (level finite)
        const int lcz    = (s == 9);             // l2c == 0
        const float lvl  = (s <= 8) ? levels[s] : levels[8];
        const float ascale = (s == 10) ? 1.f : sqrtf(-(lvl * LOG2E));
        const float inva   = 1.f / ascale;
        fused_step<<<GRID, THREADS, 0, stream>>>(
            xyz1s, xyz2s, bounds2, rL, fb,
            rRb[(s + 1) & 1],      // rR(s-1)   (s>=1; unused at s=0)
            rRb[s & 1],            // rR(s) out
            ssb[(s + 2) % 3],      // ss(s-1)   (s>=1; unused at s=0)
            ssb[s % 3],            // ss(s) accumulate (pre-zeroed by kernel s-1 / init)
            ssb[(s + 1) % 3],      // ss(s+1) zeroed for next kernel
            out, ascale, inva, has_p2, has_p1, domask, lcz);
    }
}